// Round 5
// baseline (15396.866 us; speedup 1.0000x reference)
//
#include <hip/hip_runtime.h>
#include <cstdint>
#include <cstddef>

// Seq2seq LSTM, H=1024, I=1, B=512, enc T=512, dec TL=64.
// PERSISTENT kernel: one launch runs all 576 steps. Weights staged to LDS
// once per phase (enc at t=0, dec at t=512). gates = h @ W^T as bf16 MFMA,
// 2-term weight split (w_hi + w_lo), h quantized bf16 per step, c in regs.
// Decoder scalar feedback folded into weights (rank-1). Two independent
// 128-block half-grid barriers per step (halves never share data).

#define HD    1024
#define G4    4096
#define NSTEP 576
#define TLEN  64

typedef __bf16 bf16x8 __attribute__((ext_vector_type(8)));
typedef float  f32x4  __attribute__((ext_vector_type(4)));
typedef __attribute__((address_space(1))) const unsigned int glob_u32;
typedef __attribute__((address_space(3))) unsigned int lds_u32;

__device__ __forceinline__ unsigned short f2bf(float f) {
  unsigned u = __builtin_bit_cast(unsigned, f);
  u = u + 0x7FFFu + ((u >> 16) & 1u);          // RNE
  return (unsigned short)(u >> 16);
}
__device__ __forceinline__ float bf2f(unsigned short h) {
  return __builtin_bit_cast(float, (unsigned)h << 16);
}
__device__ __forceinline__ float sigm(float x) { return 1.0f / (1.0f + __expf(-x)); }
__device__ __forceinline__ float tanh_(float x) { return 1.0f - 2.0f / (1.0f + __expf(2.0f * x)); }

// ---------------------------------------------------------------------------
// Repack Whh (optionally + Wih*linW rank-1) into per-tile swizzled bf16 hi/lo.
// dst[tile][dt][c][k ^ ((c&7)<<3)], tile=j>>3, c=g*8+(j&7), 65536 elems/tile.
__global__ __launch_bounds__(256) void prep_w(const float* __restrict__ Whh,
                                              const float* __restrict__ Wih,
                                              const float* __restrict__ linW,
                                              int fold,
                                              unsigned short* __restrict__ dst) {
  int gid  = blockIdx.x * 256 + threadIdx.x;   // 0 .. 1048575
  int rowg = gid >> 8;                          // 0..4095
  int k0   = (gid & 255) << 2;                  // 0..1020
  float4 wv = *reinterpret_cast<const float4*>(Whh + (size_t)rowg * HD + k0);
  if (fold) {
    float wi = Wih[rowg];
    float4 lw = *reinterpret_cast<const float4*>(linW + k0);
    wv.x += wi * lw.x; wv.y += wi * lw.y; wv.z += wi * lw.z; wv.w += wi * lw.w;
  }
  ushort4 hi, lo;
  hi.x = f2bf(wv.x); lo.x = f2bf(wv.x - bf2f(hi.x));
  hi.y = f2bf(wv.y); lo.y = f2bf(wv.y - bf2f(hi.y));
  hi.z = f2bf(wv.z); lo.z = f2bf(wv.z - bf2f(hi.z));
  hi.w = f2bf(wv.w); lo.w = f2bf(wv.w - bf2f(hi.w));
  int g = rowg >> 10, j = rowg & 1023;
  int tile = j >> 3, c = g * 8 + (j & 7);
  size_t base = (size_t)tile * 65536 + (size_t)c * 1024 + (size_t)(k0 ^ ((c & 7) << 3));
  *reinterpret_cast<ushort4*>(dst + base)         = hi;   // dt=0
  *reinterpret_cast<ushort4*>(dst + base + 32768) = lo;   // dt=1
}

__global__ __launch_bounds__(256) void init_out(float* __restrict__ out,
                                                const float* __restrict__ lin_b) {
  int i = blockIdx.x * 256 + threadIdx.x;
  if (i < TLEN * 512) out[i] = lin_b[0];
}

// ---------------------------------------------------------------------------
// Persistent kernel. 256 blocks x 512 threads, 1 block/CU (LDS-forced).
// Block = (rh: 256 batch rows) x (tile: 8 hidden j -> 32 gate cols).
__global__ __launch_bounds__(512, 1) void lstm_persist(
    const float* __restrict__ x,        // [512,512]
    const float* __restrict__ enc_Wih,  // [4096]
    const float* __restrict__ enc_b,
    const float* __restrict__ dec_Wih,
    const float* __restrict__ dec_b,
    const float* __restrict__ linW,     // [1024]
    const float* __restrict__ linb_p,   // [1]
    const unsigned short* __restrict__ wenc,  // [128][2][32][1024] swizzled
    const unsigned short* __restrict__ wdec,
    unsigned short* __restrict__ hA,    // [32][512][32] bf16 ping
    unsigned short* __restrict__ hB,    // pong
    float* __restrict__ p,              // [512] enc h . linW
    unsigned* __restrict__ bar,         // [64] two counters, 128B apart
    float* __restrict__ out)            // [64,512], pre-init to lin_b
{
  __shared__ __align__(16) unsigned char smem[148480];
  float* gl   = (float*)(smem + 131072);          // [128][33]
  float* wihs = (float*)(smem + 131072 + 16896);  // 32
  float* bs   = wihs + 32;                        // 32
  float* lws  = wihs + 64;                        // 8

  const int tid  = threadIdx.x;
  const int lane = tid & 63;
  const int wid  = tid >> 6;           // 0..7
  const int l15  = lane & 15;
  const int lk   = lane >> 4;          // 0..3

  const int bid  = blockIdx.x;
  const int rh   = (bid >> 2) & 1;
  const int tile = (bid >> 3) * 4 + (bid & 3);     // 0..127
  const int kblk = tile >> 2;
  const float linb = linb_p[0];
  unsigned* cnt = bar + rh * 32;                   // 128 B apart

  // A-fragment element offsets (constant across steps)
  const int rowbase = rh * 256 + wid * 32;
  size_t aoff[2];
#pragma unroll
  for (int m = 0; m < 2; ++m)
    aoff[m] = (size_t)(rowbase + m * 16 + l15) * 32 + (size_t)lk * 8;

  // B LDS byte offsets (lane-const part)
  int QH[2], QL[2];
#pragma unroll
  for (int nt = 0; nt < 2; ++nt) {
    int c = nt * 16 + l15;
    int s = (c & 7) << 4;
    int q = c * 2048 + ((lk * 16) ^ s);   // bits disjoint: + == ^
    QH[nt] = q;
    QL[nt] = 65536 + q;
  }

  // epilogue mapping: thread -> 2 rows (one per half) x 2 j
  const int rowc = tid >> 2;           // 0..127 (gl row)
  const int jq   = tid & 3;            // 2 j's: jj = jq*2 + q

  float c_reg[2][2] = {{0.f, 0.f}, {0.f, 0.f}};   // [half][q]

#define STAGE(WB, WIH, BB)                                                   \
  {                                                                          \
    glob_u32* gsrc = (glob_u32*)((WB) + (size_t)tile * 65536);               \
    lds_u32*  ldst = (lds_u32*)smem;                                         \
    _Pragma("unroll")                                                        \
    for (int i = 0; i < 16; ++i)                                             \
      __builtin_amdgcn_global_load_lds(gsrc + i * 2048 + tid * 4,            \
                                       ldst + i * 2048 + tid * 4, 16, 0, 0); \
    if (tid < 32) {                                                          \
      int gg = tid >> 3, jj = tid & 7;                                       \
      int r = gg * HD + tile * 8 + jj;                                       \
      wihs[tid] = (WIH)[r];                                                  \
      bs[tid]   = (BB)[r];                                                   \
    } else if (tid < 40) {                                                   \
      lws[tid - 32] = linW[tile * 8 + (tid - 32)];                           \
    }                                                                        \
  }

  STAGE(wenc, enc_Wih, enc_b);
  __syncthreads();

#pragma unroll 1
  for (int t = 0; t < NSTEP; ++t) {
    if (t == 512) {              // swap to decoder weights (all waves aligned)
      STAGE(wdec, dec_Wih, dec_b);
      __syncthreads();
    }
    const unsigned short* hin = (t & 1) ? hB : hA;
    unsigned short* hout      = (t & 1) ? hA : hB;

    const unsigned short* pa[2];
#pragma unroll
    for (int m = 0; m < 2; ++m) pa[m] = hin + aoff[m];

    // ---- MFMA: 256 rows x 32 gate cols, K=1024, hi+lo terms
    f32x4 acc[2][2] = {};
    bf16x8 Af[3][2], BH[2][2], BL[2][2];

#define LOADA(kk, st)                                                        \
  { _Pragma("unroll") for (int m = 0; m < 2; ++m)                            \
      Af[st][m] = *(const bf16x8*)(pa[m] + (size_t)(kk) * 16384); }
#define LOADB(kk, st)                                                        \
  { _Pragma("unroll") for (int nt = 0; nt < 2; ++nt) {                       \
      BH[st][nt] = *(const bf16x8*)(smem + (QH[nt] ^ ((kk) << 6)));          \
      BL[st][nt] = *(const bf16x8*)(smem + (QL[nt] ^ ((kk) << 6))); } }

    LOADA(0, 0); LOADA(1, 1); LOADB(0, 0);
#pragma unroll
    for (int kk = 0; kk < 32; ++kk) {
      if (kk + 2 < 32) LOADA(kk + 2, (kk + 2) % 3);
      if (kk + 1 < 32) LOADB(kk + 1, (kk + 1) & 1);
#pragma unroll
      for (int m = 0; m < 2; ++m)
#pragma unroll
        for (int nt = 0; nt < 2; ++nt) {
          acc[m][nt] = __builtin_amdgcn_mfma_f32_16x16x32_bf16(
              Af[kk % 3][m], BH[kk & 1][nt], acc[m][nt], 0, 0, 0);
          acc[m][nt] = __builtin_amdgcn_mfma_f32_16x16x32_bf16(
              Af[kk % 3][m], BL[kk & 1][nt], acc[m][nt], 0, 0, 0);
        }
    }
#undef LOADA
#undef LOADB

    // ---- two-pass epilogue (gl = [128][33] f32, fits beside weights)
#pragma unroll
    for (int half = 0; half < 2; ++half) {
      __syncthreads();     // gl free (prev pass / prev step readers done)
#pragma unroll
      for (int nt = 0; nt < 2; ++nt)
#pragma unroll
        for (int r = 0; r < 4; ++r)
          gl[(wid * 16 + lk * 4 + r) * 33 + nt * 16 + l15] = acc[half][nt][r];
      __syncthreads();

      const int grow = rh * 256 + ((rowc >> 4) << 5) + half * 16 + (rowc & 15);
      float xs;
      if (t < 512)       xs = x[(size_t)t * 512 + grow];
      else if (t == 512) xs = x[(size_t)511 * 512 + grow] - p[grow];
      else               xs = linb;

      float yp = 0.0f;
      unsigned short hw[2];
#pragma unroll
      for (int q = 0; q < 2; ++q) {
        int jj = jq * 2 + q;
        float gi = gl[rowc * 33 + jj]      + xs * wihs[jj]      + bs[jj];
        float gf = gl[rowc * 33 + 8 + jj]  + xs * wihs[8 + jj]  + bs[8 + jj];
        float gg = gl[rowc * 33 + 16 + jj] + xs * wihs[16 + jj] + bs[16 + jj];
        float go = gl[rowc * 33 + 24 + jj] + xs * wihs[24 + jj] + bs[24 + jj];
        float cn = sigm(gf) * c_reg[half][q] + sigm(gi) * tanh_(gg);
        c_reg[half][q] = cn;
        float hn = sigm(go) * tanh_(cn);
        yp += hn * lws[jj];
        hw[q] = f2bf(hn);
      }
      *reinterpret_cast<ushort2*>(hout + (size_t)kblk * 16384 + (size_t)grow * 32
                                  + (tile & 3) * 8 + jq * 2)
          = *reinterpret_cast<ushort2*>(hw);
      if (t >= 511) {
        yp += __shfl_xor(yp, 1);
        yp += __shfl_xor(yp, 2);
        if (jq == 0) {
          if (t == 511) atomicAdd(p + grow, yp);
          else          atomicAdd(out + (size_t)(t - 512) * 512 + grow, yp);
        }
      }
    }

    // ---- half-grid barrier (128 blocks; halves are fully independent)
    if (t != NSTEP - 1) {
      __syncthreads();               // all waves' stores drained to L2 (vmcnt 0)
      if (tid == 0) {
        __threadfence();             // release: buffer_wbl2 (flush XCD L2)
        atomicAdd(cnt, 1u);
        unsigned tgt = (unsigned)(t + 1) * 128u;
        while (__hip_atomic_load(cnt, __ATOMIC_RELAXED,
                                 __HIP_MEMORY_SCOPE_AGENT) < tgt)
          __builtin_amdgcn_s_sleep(2);
        __threadfence();             // acquire: buffer_inv (L1+L2)
      }
      __syncthreads();
    }
  }
#undef STAGE
}

// ---------------------------------------------------------------------------
extern "C" void kernel_launch(void* const* d_in, const int* in_sizes, int n_in,
                              void* d_out, int out_size, void* d_ws, size_t ws_size,
                              hipStream_t stream) {
  const float* x       = (const float*)d_in[0];   // [512,512,1]
  const float* enc_Wih = (const float*)d_in[1];
  const float* enc_Whh = (const float*)d_in[2];
  const float* enc_b   = (const float*)d_in[3];
  const float* dec_Wih = (const float*)d_in[4];
  const float* dec_Whh = (const float*)d_in[5];
  const float* dec_b   = (const float*)d_in[6];
  const float* lin_W   = (const float*)d_in[7];   // [1,1024]
  const float* lin_b   = (const float*)d_in[8];   // [1]
  float* out = (float*)d_out;                     // [64,512]

  uint8_t* w = (uint8_t*)d_ws;
  const size_t MB = 1u << 20;
  unsigned short* hA   = (unsigned short*)(w + 0 * MB);   // 1 MB (h0 = 0)
  unsigned short* hB   = (unsigned short*)(w + 1 * MB);   // 1 MB
  float*          p    = (float*)(w + 2 * MB);            // 2 KB
  unsigned*       bar  = (unsigned*)(w + 2 * MB + 4096);  // 256 B
  unsigned short* wenc = (unsigned short*)(w + 4 * MB);   // 16 MB
  unsigned short* wdec = (unsigned short*)(w + 20 * MB);  // 16 MB (total 36)

  hipMemsetAsync(hA, 0, MB, stream);                 // h0 = 0
  hipMemsetAsync(p, 0, 8192, stream);                // p + barrier counters
  init_out<<<128, 256, 0, stream>>>(out, lin_b);
  prep_w<<<4096, 256, 0, stream>>>(enc_Whh, enc_Wih, lin_W, 0, wenc);
  prep_w<<<4096, 256, 0, stream>>>(dec_Whh, dec_Wih, lin_W, 1, wdec);

  lstm_persist<<<256, 512, 0, stream>>>(
      x, enc_Wih, enc_b, dec_Wih, dec_b, lin_W, lin_b,
      wenc, wdec, hA, hB, p, bar, out);

  (void)in_sizes; (void)n_in; (void)out_size; (void)ws_size;
}

// Round 7
// 13127.525 us; speedup vs baseline: 1.1729x; 1.1729x over previous
//
#include <hip/hip_runtime.h>
#include <cstdint>
#include <cstddef>

// Seq2seq LSTM, H=1024, I=1, B=512, enc T=512, dec TL=64.
// PERSISTENT kernel v3: weights in LDS (staged once/phase), gates via bf16
// MFMA (2-term weight split), register-only epilogue (shfl gate exchange),
// c in regs, h ping-pong [tile][row][8] bf16, flag-broadcast grid barrier.

#define HD    1024
#define NSTEP 576
#define TLEN  64

typedef __bf16 bf16x8 __attribute__((ext_vector_type(8)));
typedef float  f32x4  __attribute__((ext_vector_type(4)));
typedef __attribute__((address_space(1))) const unsigned int glob_u32;
typedef __attribute__((address_space(3))) unsigned int lds_u32;

__device__ __forceinline__ unsigned short f2bf(float f) {
  unsigned u = __builtin_bit_cast(unsigned, f);
  u = u + 0x7FFFu + ((u >> 16) & 1u);          // RNE
  return (unsigned short)(u >> 16);
}
__device__ __forceinline__ float bf2f(unsigned short h) {
  return __builtin_bit_cast(float, (unsigned)h << 16);
}
__device__ __forceinline__ float sigm(float x) { return 1.0f / (1.0f + __expf(-x)); }
__device__ __forceinline__ float tanh_(float x) { return 1.0f - 2.0f / (1.0f + __expf(2.0f * x)); }

// ---------------------------------------------------------------------------
// Repack Whh (optionally + Wih*linW rank-1) into per-tile swizzled bf16 hi/lo.
// dst[tile][dt][c][k ^ ((c&7)<<3)], tile=j>>3, c=g*8+(j&7), 65536 elems/tile.
__global__ __launch_bounds__(256) void prep_w(const float* __restrict__ Whh,
                                              const float* __restrict__ Wih,
                                              const float* __restrict__ linW,
                                              int fold,
                                              unsigned short* __restrict__ dst) {
  int gid  = blockIdx.x * 256 + threadIdx.x;   // 0 .. 1048575
  int rowg = gid >> 8;                          // 0..4095
  int k0   = (gid & 255) << 2;                  // 0..1020
  float4 wv = *reinterpret_cast<const float4*>(Whh + (size_t)rowg * HD + k0);
  if (fold) {
    float wi = Wih[rowg];
    float4 lw = *reinterpret_cast<const float4*>(linW + k0);
    wv.x += wi * lw.x; wv.y += wi * lw.y; wv.z += wi * lw.z; wv.w += wi * lw.w;
  }
  ushort4 hi, lo;
  hi.x = f2bf(wv.x); lo.x = f2bf(wv.x - bf2f(hi.x));
  hi.y = f2bf(wv.y); lo.y = f2bf(wv.y - bf2f(hi.y));
  hi.z = f2bf(wv.z); lo.z = f2bf(wv.z - bf2f(hi.z));
  hi.w = f2bf(wv.w); lo.w = f2bf(wv.w - bf2f(hi.w));
  int g = rowg >> 10, j = rowg & 1023;
  int tile = j >> 3, c = g * 8 + (j & 7);
  size_t base = (size_t)tile * 65536 + (size_t)c * 1024 + (size_t)(k0 ^ ((c & 7) << 3));
  *reinterpret_cast<ushort4*>(dst + base)         = hi;   // dt=0
  *reinterpret_cast<ushort4*>(dst + base + 32768) = lo;   // dt=1
}

__global__ __launch_bounds__(256) void init_out(float* __restrict__ out,
                                                const float* __restrict__ lin_b) {
  int i = blockIdx.x * 256 + threadIdx.x;
  if (i < TLEN * 512) out[i] = lin_b[0];
}

// ---------------------------------------------------------------------------
// Persistent kernel. 256 blocks x 512 threads, 1 block/CU (128 KB LDS).
// Block = (rh: 256 batch rows) x (tile: 8 hidden j -> 32 gate cols).
// Waves: wid owns rows [rowbase, rowbase+32), 2 m-tiles x 2 nt x 32 kk.
__global__ __launch_bounds__(512, 2) void lstm_persist(
    const float* __restrict__ x,        // [512,512]
    const float* __restrict__ enc_Wih,  // [4096]
    const float* __restrict__ enc_b,
    const float* __restrict__ dec_Wih,
    const float* __restrict__ dec_b,
    const float* __restrict__ linW,     // [1024]
    const float* __restrict__ linb_p,   // [1]
    const unsigned short* __restrict__ wenc,  // [128][2][32][1024] swizzled
    const unsigned short* __restrict__ wdec,
    unsigned short* __restrict__ hA,    // [128][512][8] bf16 ping
    unsigned short* __restrict__ hB,    // pong
    float* __restrict__ p,              // [512] enc h . linW
    unsigned* __restrict__ bar,         // go[0],go[32]; flags at +128
    float* __restrict__ out)            // [64,512], pre-init to lin_b
{
  __shared__ __align__(16) unsigned char smem[131072];   // weight image only
  const int tid  = threadIdx.x;
  const int lane = tid & 63;
  const int wid  = tid >> 6;           // 0..7
  const int l15  = lane & 15;
  const int lk   = lane >> 4;          // 0..3
  const int msel = (l15 >> 3) & 1;     // 0: m0 rows, 1: m1 rows (epilogue)
  const int jj   = l15 & 7;            // hidden j within tile (epilogue)

  const int bid  = blockIdx.x;
  const int rh   = (bid >> 2) & 1;                 // rh0 on XCD 0-3, rh1 on 4-7
  const int tile = (bid >> 3) * 4 + (bid & 3);     // 0..127 (== slot in half)
  const float linb = linb_p[0];

  const int rowbase = rh * 256 + wid * 32;
  // A-fragment elem offsets in h[tile_k][row][8]: tile_k = kk*4+lk
  size_t aoff[2];
#pragma unroll
  for (int m = 0; m < 2; ++m)
    aoff[m] = (size_t)lk * 4096 + (size_t)(rowbase + m * 16 + l15) * 8;

  // B LDS byte offsets (lane-const part), same validated swizzle
  int QH[2], QL[2];
#pragma unroll
  for (int nt = 0; nt < 2; ++nt) {
    int c = nt * 16 + l15;
    int s = (c & 7) << 4;
    int q = c * 2048 + ((lk * 16) ^ s);   // bits disjoint: + == ^
    QH[nt] = q;
    QL[nt] = 65536 + q;
  }

  // epilogue: this lane updates rows erow..erow+3, hidden col tile*8+jj
  const int erow = rowbase + msel * 16 + lk * 4;
  const size_t hobase = (size_t)tile * 4096 + (size_t)erow * 8 + jj;

  float c_reg[4] = {0.f, 0.f, 0.f, 0.f};
  float wih_r[4], b_r[4], lw_r;

#define STAGE(WB)                                                            \
  {                                                                          \
    glob_u32* gsrc = (glob_u32*)((WB) + (size_t)tile * 65536);               \
    lds_u32*  ldst = (lds_u32*)smem;                                         \
    _Pragma("unroll")                                                        \
    for (int i = 0; i < 16; ++i)                                             \
      __builtin_amdgcn_global_load_lds(gsrc + i * 2048 + tid * 4,            \
                                       ldst + i * 2048 + tid * 4, 16, 0, 0); \
  }
#define WREGS(WIH, BB)                                                       \
  {                                                                          \
    _Pragma("unroll")                                                        \
    for (int g = 0; g < 4; ++g) {                                            \
      wih_r[g] = (WIH)[g * HD + tile * 8 + jj];                              \
      b_r[g]   = (BB)[g * HD + tile * 8 + jj];                               \
    }                                                                        \
    lw_r = linW[tile * 8 + jj];                                              \
  }

  STAGE(wenc);
  WREGS(enc_Wih, enc_b);
  __syncthreads();

#pragma unroll 1
  for (int t = 0; t < NSTEP; ++t) {
    if (t == 512) {              // swap to decoder weights (all blocks aligned)
      STAGE(wdec);
      WREGS(dec_Wih, dec_b);
      __syncthreads();
    }
    const unsigned short* hin = (t & 1) ? hB : hA;
    unsigned short* hout      = (t & 1) ? hA : hB;

    // ---- MFMA: 256 rows x 32 gate cols, K=1024, hi+lo terms
    f32x4 acc[2][2] = {};
    bf16x8 Af[4][2], BH[2][2], BL[2][2];

#define LOADA(kk, st)                                                        \
  { _Pragma("unroll") for (int m = 0; m < 2; ++m)                            \
      Af[st][m] = *(const bf16x8*)(hin + (size_t)(kk) * 16384 + aoff[m]); }
#define LOADB(kk, st)                                                        \
  { _Pragma("unroll") for (int nt = 0; nt < 2; ++nt) {                       \
      BH[st][nt] = *(const bf16x8*)(smem + (QH[nt] ^ ((kk) << 6)));          \
      BL[st][nt] = *(const bf16x8*)(smem + (QL[nt] ^ ((kk) << 6))); } }

    LOADA(0, 0); LOADA(1, 1); LOADA(2, 2); LOADB(0, 0);
#pragma unroll
    for (int kk = 0; kk < 32; ++kk) {
      if (kk + 3 < 32) LOADA(kk + 3, (kk + 3) & 3);
      if (kk + 1 < 32) LOADB(kk + 1, (kk + 1) & 1);
#pragma unroll
      for (int m = 0; m < 2; ++m)
#pragma unroll
        for (int nt = 0; nt < 2; ++nt) {
          acc[m][nt] = __builtin_amdgcn_mfma_f32_16x16x32_bf16(
              Af[kk & 3][m], BH[kk & 1][nt], acc[m][nt], 0, 0, 0);
          acc[m][nt] = __builtin_amdgcn_mfma_f32_16x16x32_bf16(
              Af[kk & 3][m], BL[kk & 1][nt], acc[m][nt], 0, 0, 0);
        }
    }
#undef LOADA
#undef LOADB

    // ---- register epilogue. D-layout: lane holds D[lk*4+r][l15] (m-tiles).
    // Block cols: nt*16+l15 -> gate (col>>3), j (col&7). Pair lanes (j, j+8)
    // exchange so lane(msel=0) updates m0 rows, lane(msel=1) m1 rows.
    f32x4 sv0 = msel ? acc[0][0] : acc[1][0];
    f32x4 sv1 = msel ? acc[0][1] : acc[1][1];
    f32x4 w0, w1;
#pragma unroll
    for (int i = 0; i < 4; ++i) {
      w0[i] = __shfl_xor(sv0[i], 8);
      w1[i] = __shfl_xor(sv1[i], 8);
    }
    f32x4 iv = msel ? w0 : acc[0][0];
    f32x4 fv = msel ? acc[1][0] : w0;
    f32x4 gv = msel ? w1 : acc[0][1];
    f32x4 ov = msel ? acc[1][1] : w1;

    f32x4 xs;
    if (t < 512) {
      xs = *(const f32x4*)(x + (size_t)t * 512 + erow);
    } else if (t == 512) {
      f32x4 xl = *(const f32x4*)(x + (size_t)511 * 512 + erow);
      f32x4 pl = *(const f32x4*)(p + erow);
      xs = xl - pl;
    } else {
      xs = (f32x4){linb, linb, linb, linb};
    }

    float yp[4];
#pragma unroll
    for (int r = 0; r < 4; ++r) {
      float gi  = iv[r] + xs[r] * wih_r[0] + b_r[0];
      float gf  = fv[r] + xs[r] * wih_r[1] + b_r[1];
      float gg  = gv[r] + xs[r] * wih_r[2] + b_r[2];
      float go2 = ov[r] + xs[r] * wih_r[3] + b_r[3];
      float cn = sigm(gf) * c_reg[r] + sigm(gi) * tanh_(gg);
      c_reg[r] = cn;
      float hn = sigm(go2) * tanh_(cn);
      hout[hobase + (size_t)r * 8] = f2bf(hn);
      yp[r] = hn * lw_r;
    }
    if (t >= 511) {
#pragma unroll
      for (int r = 0; r < 4; ++r) {
        yp[r] += __shfl_xor(yp[r], 1);
        yp[r] += __shfl_xor(yp[r], 2);
        yp[r] += __shfl_xor(yp[r], 4);
      }
      if (jj == 0) {
        float* dst = (t == 511) ? (p + erow)
                                : (out + (size_t)(t - 512) * 512 + erow);
#pragma unroll
        for (int r = 0; r < 4; ++r) atomicAdd(dst + r, yp[r]);
      }
    }

    // ---- flag-broadcast half-grid barrier (128 blocks; halves independent)
    if (t != NSTEP - 1) {
      __syncthreads();             // each wave's h-stores drained (vmcnt 0)
      if (wid == 0) {
        const unsigned tgt = (unsigned)t + 1u;
        unsigned* flags = bar + 128 + rh * 128;
        if (lane == 0) {
          __threadfence();         // release: L2 writeback (h visible at LIC)
          __hip_atomic_store(flags + tile, tgt, __ATOMIC_RELAXED,
                             __HIP_MEMORY_SCOPE_AGENT);
        }
        if (tile == 0) {           // leader: poll all 128 flags, 2 per lane
          for (;;) {
            unsigned a = __hip_atomic_load(flags + lane, __ATOMIC_RELAXED,
                                           __HIP_MEMORY_SCOPE_AGENT);
            unsigned b = __hip_atomic_load(flags + 64 + lane, __ATOMIC_RELAXED,
                                           __HIP_MEMORY_SCOPE_AGENT);
            if (__all((a >= tgt) && (b >= tgt))) break;
            __builtin_amdgcn_s_sleep(1);
          }
          if (lane == 0)
            __hip_atomic_store(bar + rh * 32, tgt, __ATOMIC_RELAXED,
                               __HIP_MEMORY_SCOPE_AGENT);
        }
        if (lane == 0) {
          while (__hip_atomic_load(bar + rh * 32, __ATOMIC_RELAXED,
                                   __HIP_MEMORY_SCOPE_AGENT) < tgt)
            __builtin_amdgcn_s_sleep(2);
          __threadfence();         // acquire: inv L1/L2 (fresh h from LIC)
        }
      }
      __syncthreads();
    }
  }
#undef STAGE
#undef WREGS
}

// ---------------------------------------------------------------------------
extern "C" void kernel_launch(void* const* d_in, const int* in_sizes, int n_in,
                              void* d_out, int out_size, void* d_ws, size_t ws_size,
                              hipStream_t stream) {
  const float* x       = (const float*)d_in[0];   // [512,512,1]
  const float* enc_Wih = (const float*)d_in[1];
  const float* enc_Whh = (const float*)d_in[2];
  const float* enc_b   = (const float*)d_in[3];
  const float* dec_Wih = (const float*)d_in[4];
  const float* dec_Whh = (const float*)d_in[5];
  const float* dec_b   = (const float*)d_in[6];
  const float* lin_W   = (const float*)d_in[7];   // [1,1024]
  const float* lin_b   = (const float*)d_in[8];   // [1]
  float* out = (float*)d_out;                     // [64,512]

  uint8_t* w = (uint8_t*)d_ws;
  const size_t MB = 1u << 20;
  unsigned short* hA   = (unsigned short*)(w + 0 * MB);   // 1 MB (h0 = 0)
  unsigned short* hB   = (unsigned short*)(w + 1 * MB);   // 1 MB
  float*          p    = (float*)(w + 2 * MB);            // 2 KB
  unsigned*       bar  = (unsigned*)(w + 2 * MB + 4096);  // go + flags, <2 KB
  unsigned short* wenc = (unsigned short*)(w + 4 * MB);   // 16 MB
  unsigned short* wdec = (unsigned short*)(w + 20 * MB);  // 16 MB (total 36)

  hipMemsetAsync(hA, 0, MB, stream);                 // h0 = 0
  hipMemsetAsync(p, 0, 8192, stream);                // p + go + flags
  init_out<<<128, 256, 0, stream>>>(out, lin_b);
  prep_w<<<4096, 256, 0, stream>>>(enc_Whh, enc_Wih, lin_W, 0, wenc);
  prep_w<<<4096, 256, 0, stream>>>(dec_Whh, dec_Wih, lin_W, 1, wdec);

  lstm_persist<<<256, 512, 0, stream>>>(
      x, enc_Wih, enc_b, dec_Wih, dec_b, lin_W, lin_b,
      wenc, wdec, hA, hB, p, bar, out);

  (void)in_sizes; (void)n_in; (void)out_size; (void)ws_size;
}